// Round 1
// baseline (258.672 us; speedup 1.0000x reference)
//
#include <hip/hip_runtime.h>

// RFNorm: out = (0.5*groupnorm(x) + 0.5*tokennorm(x)) * weight + bias
// x: (B=8, T=4000, D=1024) fp32; groups are G=5 contiguous blocks of L=T/G tokens.
// Group (b,g) covers a contiguous slab of L*D floats at offset (b*G+g)*L*D.

#define EPS 1e-5f
#define NUM_G 5
#define CHUNKS_PER_GROUP 32

// ---------------- Kernel 1: per-group sum / sumsq -> d_ws[2*group + {0,1}] ----
__global__ __launch_bounds__(256) void group_stats_kernel(
    const float4* __restrict__ x, float* __restrict__ gstats,
    int vec4_per_group) {
  const int group = blockIdx.x / CHUNKS_PER_GROUP;
  const int chunk = blockIdx.x % CHUNKS_PER_GROUP;
  const int per_chunk = vec4_per_group / CHUNKS_PER_GROUP;
  const long base = (long)group * vec4_per_group + (long)chunk * per_chunk;

  float s = 0.f, sq = 0.f;
  for (int i = threadIdx.x; i < per_chunk; i += 256) {
    float4 v = x[base + i];
    s  += (v.x + v.y) + (v.z + v.w);
    sq += (v.x * v.x + v.y * v.y) + (v.z * v.z + v.w * v.w);
  }
  // wave64 reduce
  #pragma unroll
  for (int off = 32; off > 0; off >>= 1) {
    s  += __shfl_down(s,  off, 64);
    sq += __shfl_down(sq, off, 64);
  }
  __shared__ float ls[4], lq[4];
  const int wave = threadIdx.x >> 6, lane = threadIdx.x & 63;
  if (lane == 0) { ls[wave] = s; lq[wave] = sq; }
  __syncthreads();
  if (threadIdx.x == 0) {
    float ts = (ls[0] + ls[1]) + (ls[2] + ls[3]);
    float tq = (lq[0] + lq[1]) + (lq[2] + lq[3]);
    atomicAdd(&gstats[2 * group + 0], ts);
    atomicAdd(&gstats[2 * group + 1], tq);
  }
}

// ---------------- Kernel 2: per-token norm + blend + affine -------------------
// One block per token row; 256 threads x float4 == D=1024 elements exactly.
__global__ __launch_bounds__(256) void rfnorm_out_kernel(
    const float4* __restrict__ x, const float* __restrict__ gstats,
    const float4* __restrict__ weight, const float4* __restrict__ bias,
    float4* __restrict__ out, int T, int L, float invD, float invNg) {
  const int row = blockIdx.x;     // b*T + t
  const int t = row % T;
  const int b = row / T;
  const int group = b * NUM_G + (t / L);
  const long base = (long)row * 256;

  float4 v = x[base + threadIdx.x];
  float s  = (v.x + v.y) + (v.z + v.w);
  float sq = (v.x * v.x + v.y * v.y) + (v.z * v.z + v.w * v.w);
  #pragma unroll
  for (int off = 32; off > 0; off >>= 1) {
    s  += __shfl_down(s,  off, 64);
    sq += __shfl_down(sq, off, 64);
  }
  __shared__ float ls[4], lq[4];
  const int wave = threadIdx.x >> 6, lane = threadIdx.x & 63;
  if (lane == 0) { ls[wave] = s; lq[wave] = sq; }
  __syncthreads();
  const float ts = (ls[0] + ls[1]) + (ls[2] + ls[3]);
  const float tq = (lq[0] + lq[1]) + (lq[2] + lq[3]);

  const float tmu  = ts * invD;
  const float tvar = tq * invD - tmu * tmu;
  const float trs  = rsqrtf(tvar + EPS) * 0.5f;   // fold RFN=0.5 into rstd

  const float gsum = gstats[2 * group + 0];
  const float gsq  = gstats[2 * group + 1];
  const float gmu  = gsum * invNg;
  const float gvar = gsq * invNg - gmu * gmu;
  const float grs  = rsqrtf(gvar + EPS) * 0.5f;

  const float4 w  = weight[threadIdx.x];
  const float4 bb = bias[threadIdx.x];

  float4 o;
  o.x = ((v.x - gmu) * grs + (v.x - tmu) * trs) * w.x + bb.x;
  o.y = ((v.y - gmu) * grs + (v.y - tmu) * trs) * w.y + bb.y;
  o.z = ((v.z - gmu) * grs + (v.z - tmu) * trs) * w.z + bb.z;
  o.w = ((v.w - gmu) * grs + (v.w - tmu) * trs) * w.w + bb.w;
  out[base + threadIdx.x] = o;
}

extern "C" void kernel_launch(void* const* d_in, const int* in_sizes, int n_in,
                              void* d_out, int out_size, void* d_ws, size_t ws_size,
                              hipStream_t stream) {
  const float* x      = (const float*)d_in[0];
  // d_in[1] = mask (G, T/G) int32 ones — only shape matters; G hardcoded = 5.
  const float* weight = (const float*)d_in[2];
  const float* bias   = (const float*)d_in[3];
  float* out          = (float*)d_out;
  float* gstats       = (float*)d_ws;

  const int D = in_sizes[2];                 // 1024
  const int T = in_sizes[1];                 // mask flat size = G*(T/G) = T = 4000
  const int B = in_sizes[0] / (T * D);       // 8
  const int L = T / NUM_G;                   // 800
  const long Ng = (long)L * D;               // 819200 elems per group
  const int vec4_per_group = (int)(Ng / 4);  // 204800

  // ws is poisoned 0xAA before every call — zero the accumulators.
  hipMemsetAsync(gstats, 0, (size_t)(B * NUM_G * 2) * sizeof(float), stream);

  dim3 blk(256);
  dim3 grid1(B * NUM_G * CHUNKS_PER_GROUP);
  group_stats_kernel<<<grid1, blk, 0, stream>>>(
      (const float4*)x, gstats, vec4_per_group);

  dim3 grid2(B * T);
  rfnorm_out_kernel<<<grid2, blk, 0, stream>>>(
      (const float4*)x, gstats, (const float4*)weight, (const float4*)bias,
      (float4*)out, T, L, 1.0f / D, 1.0f / (float)Ng);
}